// Round 2
// baseline (69.156 us; speedup 1.0000x reference)
//
#include <hip/hip_runtime.h>

// ball_query(radius=3.4, nsample=5) — one thread per query point.
// B=8, N=4096, D=3. Output [B, N, 5] int32.
//
// Semantics (pointnet2 CUDA kernel, matched to the jnp reference):
//   scan k in order; first k with d2 < r2 fills ALL 5 slots, each further hit
//   overwrites slot cnt; stop after 5 hits. Self-distance is exactly 0 with
//   the reference's formula, so >=1 hit always exists.
//
// d2 must match the reference bit-close at the r2 boundary:
//   d2 = (sq_q + sq_k) - 2*dot, with sq = (x0*x0 + x1*x1) + x2*x2 and
//   dot = (x0*y0 + x1*y1) + x2*y2, separately-rounded float32 (no fma) —
//   hence file-scope fp contract(off).

#pragma clang fp contract(off)

#define BQ_N 4096
#define BQ_B 8
#define BQ_NS 5

__global__ __launch_bounds__(256) void ball_query_kernel(
    const float* __restrict__ x, int* __restrict__ out, float r2) {
  int gid = blockIdx.x * blockDim.x + threadIdx.x;  // [0, B*N)
  int b = gid >> 12;        // / 4096
  int q = gid & (BQ_N - 1); // % 4096

  const float* xb = x + (size_t)b * BQ_N * 3;

  const float qx = xb[q * 3 + 0];
  const float qy = xb[q * 3 + 1];
  const float qz = xb[q * 3 + 2];
  const float sq_q = (qx * qx + qy * qy) + qz * qz;

  int s0 = 0, s1 = 0, s2 = 0, s3 = 0, s4 = 0;
  int cnt = 0;

  for (int k = 0; k < BQ_N; ++k) {
    const float kx = xb[k * 3 + 0];
    const float ky = xb[k * 3 + 1];
    const float kz = xb[k * 3 + 2];
    const float sq_k = (kx * kx + ky * ky) + kz * kz;
    const float dot = (qx * kx + qy * ky) + qz * kz;
    const float d2 = (sq_q + sq_k) - 2.0f * dot;
    if (d2 < r2) {
      if (cnt == 0) {
        s0 = s1 = s2 = s3 = s4 = k;
      } else if (cnt == 1) {
        s1 = k;
      } else if (cnt == 2) {
        s2 = k;
      } else if (cnt == 3) {
        s3 = k;
      } else {
        s4 = k;
      }
      if (++cnt == BQ_NS) break;
    }
  }

  const int base = gid * BQ_NS;
  out[base + 0] = s0;
  out[base + 1] = s1;
  out[base + 2] = s2;
  out[base + 3] = s3;
  out[base + 4] = s4;
}

extern "C" void kernel_launch(void* const* d_in, const int* in_sizes, int n_in,
                              void* d_out, int out_size, void* d_ws, size_t ws_size,
                              hipStream_t stream) {
  const float* x = (const float*)d_in[0];
  int* out = (int*)d_out;
  const float r2 = 3.4f * 3.4f;  // 11.56

  const int total = BQ_B * BQ_N;          // 32768 threads
  const int block = 256;
  const int grid = total / block;         // 128 blocks
  ball_query_kernel<<<grid, block, 0, stream>>>(x, out, r2);
}

// Round 3
// 62.568 us; speedup vs baseline: 1.1053x; 1.1053x over previous
//
#include <hip/hip_runtime.h>

// ball_query(radius=3.4, nsample=5) — one thread per query point.
// B=8, N=4096, D=3. Output [B, N, 5] int32.
//
// Round 3: chunked branchless scan. The round-2 kernel serialized a
// load->compute->branch dependent chain per point (~150-300 cy each); outlier
// queries scan 100-200+ points -> ~25 µs worst-wave. Here we process 16
// points/chunk: 12 independent float4 loads (pipelined, wave-uniform ->
// L1 broadcast), branchless slot recording, wave-wide __all early exit.
//
// d2 must match the numpy reference at the r2 boundary:
//   d2 = (sq_q + sq_k) - 2*dot, sq/dot separately-rounded f32 (no fma) —
//   file-scope fp contract(off). Self-distance is exactly 0 with this
//   expression, so every query has >=1 hit.

#pragma clang fp contract(off)

#define BQ_N 4096
#define BQ_B 8
#define BQ_NS 5
#define CHUNK 16  // points per early-exit chunk; 16*3 floats = 12 float4 loads

__global__ __launch_bounds__(64) void ball_query_kernel(
    const float* __restrict__ x, int* __restrict__ out, float r2) {
  const int gid = blockIdx.x * 64 + threadIdx.x;  // [0, B*N)
  const int b = gid >> 12;         // / 4096
  const int q = gid & (BQ_N - 1);  // % 4096

  const float* xb = x + (size_t)b * BQ_N * 3;

  const float qx = xb[q * 3 + 0];
  const float qy = xb[q * 3 + 1];
  const float qz = xb[q * 3 + 2];
  const float sq_q = (qx * qx + qy * qy) + qz * qz;

  int s0 = 0, s1 = 0, s2 = 0, s3 = 0, s4 = 0;
  int cnt = 0;

  for (int k0 = 0; k0 < BQ_N; k0 += CHUNK) {
    // Load 16 points = 48 floats = 12 float4 (wave-uniform addresses,
    // 16B-aligned: k0*12 bytes, k0 % 16 == 0).
    float f[CHUNK * 3];
    const float4* p = (const float4*)(xb + k0 * 3);
#pragma unroll
    for (int i = 0; i < (CHUNK * 3) / 4; ++i) {
      *(float4*)&f[i * 4] = p[i];
    }

#pragma unroll
    for (int j = 0; j < CHUNK; ++j) {
      const float kx = f[3 * j + 0];
      const float ky = f[3 * j + 1];
      const float kz = f[3 * j + 2];
      const float sqk = (kx * kx + ky * ky) + kz * kz;
      const float dot = (qx * kx + qy * ky) + qz * kz;
      const float d2 = (sq_q + sqk) - 2.0f * dot;
      const bool h = d2 < r2;
      const int kk = k0 + j;
      // j-th hit lands in slot j (branchless); fill handled post-loop.
      s0 = (h && cnt == 0) ? kk : s0;
      s1 = (h && cnt == 1) ? kk : s1;
      s2 = (h && cnt == 2) ? kk : s2;
      s3 = (h && cnt == 3) ? kk : s3;
      s4 = (h && cnt == 4) ? kk : s4;
      cnt += h ? 1 : 0;
    }
    if (__all(cnt >= BQ_NS)) break;
  }

  // Remaining slots hold the FIRST found index (cnt >= 1 always: self-hit).
  if (cnt <= 1) s1 = s0;
  if (cnt <= 2) s2 = s0;
  if (cnt <= 3) s3 = s0;
  if (cnt <= 4) s4 = s0;

  const int base = gid * BQ_NS;
  out[base + 0] = s0;
  out[base + 1] = s1;
  out[base + 2] = s2;
  out[base + 3] = s3;
  out[base + 4] = s4;
}

extern "C" void kernel_launch(void* const* d_in, const int* in_sizes, int n_in,
                              void* d_out, int out_size, void* d_ws, size_t ws_size,
                              hipStream_t stream) {
  const float* x = (const float*)d_in[0];
  int* out = (int*)d_out;
  const float r2 = 3.4f * 3.4f;  // 11.56

  const int total = BQ_B * BQ_N;  // 32768 threads
  const int block = 64;           // 1 wave/block -> 512 blocks over 256 CUs
  const int grid = total / block;
  ball_query_kernel<<<grid, block, 0, stream>>>(x, out, r2);
}

// Round 4
// 55.916 us; speedup vs baseline: 1.2368x; 1.1190x over previous
//
#include <hip/hip_runtime.h>

// ball_query(radius=3.4, nsample=5) — ONE WAVE PER QUERY.
// B=8, N=4096, D=3. Output [B, N, 5] int32.
//
// Round 4: the thread-per-query scan made the whole wave crawl at the pace of
// its worst lane (outlier queries scan 100s of points sequentially). Now 64
// lanes test 64 consecutive points per iteration; __ballot + popcount gives
// each hit its scan-order rank; ranks 0..4 store directly. cnt (wave-uniform)
// reaches >=5 after ~1 iteration for nearly all queries (hit prob ~0.88).
//
// d2 must match the numpy reference at the r2 boundary:
//   d2 = (sq_q + sq_k) - 2*dot, sq/dot separately-rounded f32 (no fma) —
//   file-scope fp contract(off). Self-distance is exactly 0 with this
//   expression, so every query has >=1 hit (first-hit fill always valid).

#pragma clang fp contract(off)

#define BQ_N 4096
#define BQ_B 8
#define BQ_NS 5

__global__ __launch_bounds__(256) void ball_query_kernel(
    const float* __restrict__ x, int* __restrict__ out, float r2) {
  const int wid = (blockIdx.x * 256 + threadIdx.x) >> 6;  // global wave = query
  const int lane = threadIdx.x & 63;
  const int b = wid >> 12;         // / 4096
  const int q = wid & (BQ_N - 1);  // % 4096

  const float* xb = x + (size_t)b * BQ_N * 3;

  const float qx = xb[q * 3 + 0];
  const float qy = xb[q * 3 + 1];
  const float qz = xb[q * 3 + 2];
  const float sq_q = (qx * qx + qy * qy) + qz * qz;

  const int base = wid * BQ_NS;
  int cnt = 0;    // wave-uniform (popcount of ballots)
  int first = 0;  // index of first hit (valid once cnt>0)
  bool have_first = false;

  for (int k0 = 0; k0 < BQ_N; k0 += 64) {
    const int k = k0 + lane;
    const float kx = xb[k * 3 + 0];
    const float ky = xb[k * 3 + 1];
    const float kz = xb[k * 3 + 2];
    const float sqk = (kx * kx + ky * ky) + kz * kz;
    const float dot = (qx * kx + qy * ky) + qz * kz;
    const float d2 = (sq_q + sqk) - 2.0f * dot;
    const bool h = d2 < r2;

    const unsigned long long m = __ballot(h);
    if (h) {
      const unsigned long long below = ((unsigned long long)1 << lane) - 1ull;
      const int rank = cnt + __popcll(m & below);
      if (rank < BQ_NS) out[base + rank] = k;
    }
    if (!have_first && m != 0ull) {
      first = k0 + __ffsll((long long)m) - 1;
      have_first = true;
    }
    cnt += __popcll(m);
    if (cnt >= BQ_NS) break;
  }

  // Unfilled slots hold the FIRST found index (cnt >= 1 always: self-hit).
  if (lane == 0 && cnt < BQ_NS) {
    for (int j = (cnt < 1 ? 1 : cnt); j < BQ_NS; ++j) out[base + j] = first;
  }
}

extern "C" void kernel_launch(void* const* d_in, const int* in_sizes, int n_in,
                              void* d_out, int out_size, void* d_ws, size_t ws_size,
                              hipStream_t stream) {
  const float* x = (const float*)d_in[0];
  int* out = (int*)d_out;
  const float r2 = 3.4f * 3.4f;  // 11.56

  const int total_waves = BQ_B * BQ_N;     // 32768 queries, 1 wave each
  const int block = 256;                   // 4 waves/block
  const int grid = total_waves / 4;        // 8192 blocks
  ball_query_kernel<<<grid, block, 0, stream>>>(x, out, r2);
}